// Round 1
// baseline (613.160 us; speedup 1.0000x reference)
//
#include <hip/hip_runtime.h>

constexpr float kAlpha = 0.1f;
constexpr float kBeta  = 1.1f;
constexpr int   kC     = 16;
constexpr int   kD     = 512;
constexpr float kEps   = 1e-8f;

// ws layout (float offsets)
constexpr int SUMS_OFF = 0;       // kC*kD = 8192 floats
constexpr int CNT_OFF  = 8192;    // 16
constexpr int TOT_OFF  = 8208;    // 1
constexpr int CN_OFF   = 8224;    // 8192 (16B aligned: 8224*4 = 32896)
constexpr int MSK_OFF  = 16416;   // 16 (stored as unsigned)
constexpr int SCL_OFF  = 16432;   // [0]=denom, [1]=num_pairs
constexpr int ZERO_FLOATS = 8209; // sums + cnt + total

// ---------------------------------------------------------------- K1: class sums + counts
__global__ __launch_bounds__(256) void k1_sums(const float* __restrict__ emb,
                                               const int* __restrict__ labels,
                                               float* __restrict__ sums,
                                               float* __restrict__ cnt,
                                               int N, int rows_per_block) {
    __shared__ float2 lsum2[kC * kD / 2];   // 32 KB
    __shared__ float  lcnt[kC];
    int tid = threadIdx.x;
    float* lf = (float*)lsum2;
    for (int i = tid; i < kC * kD; i += 256) lf[i] = 0.f;
    if (tid < kC) lcnt[tid] = 0.f;
    __syncthreads();

    int r0 = blockIdx.x * rows_per_block;
    int r1 = min(r0 + rows_per_block, N);
    const float2* e2 = (const float2*)emb;
    for (int r = r0; r < r1; ++r) {
        int l = labels[r];                         // wave-uniform -> scalar load
        float2 v = e2[(size_t)r * (kD / 2) + tid]; // coalesced 8B/lane
        float2* p = &lsum2[l * (kD / 2) + tid];    // 2-way banks = free
        p->x += v.x;
        p->y += v.y;
        if (tid == 0) lcnt[l] += 1.f;
    }
    __syncthreads();
    for (int i = tid; i < kC * kD; i += 256) atomicAdd(&sums[i], lf[i]);
    if (tid < kC) atomicAdd(&cnt[tid], lcnt[tid]);
}

// ---------------------------------------------------------------- K2: centroids, pair logic (1 block)
__global__ __launch_bounds__(256) void k2_cent(const float* __restrict__ sums,
                                               const float* __restrict__ cnt_g,
                                               float* __restrict__ cn_g,
                                               unsigned* __restrict__ mask_g,
                                               float* __restrict__ scal) {
    __shared__ __align__(16) float lcn[kC * kD];  // 32 KB
    __shared__ float lcnt[kC];
    __shared__ float red[256];
    __shared__ float norms[kC];
    __shared__ float pdm[kC * kC];
    int tid = threadIdx.x;
    if (tid < kC) lcnt[tid] = cnt_g[tid];
    __syncthreads();

    // centroid = sums / max(cnt,1); accumulate squared norm (16 threads/class)
    int c = tid >> 4, sub = tid & 15;
    float invc = 1.f / fmaxf(lcnt[c], 1.f);
    float sq = 0.f;
    for (int d = sub; d < kD; d += 16) {
        float v = sums[c * kD + d] * invc;
        lcn[c * kD + d] = v;
        sq += v * v;
    }
    red[tid] = sq;
    __syncthreads();
    if (tid < kC) {
        float t = 0.f;
        for (int k = 0; k < 16; ++k) t += red[tid * 16 + k];
        norms[tid] = fmaxf(sqrtf(t), kEps);
    }
    __syncthreads();
    // normalize, write cn to global
    for (int i = tid; i < kC * kD; i += 256) {
        float v = lcn[i] / norms[i / kD];
        lcn[i] = v;
        cn_g[i] = v;
    }
    __syncthreads();
    // pairwise cos-dist: thread (i,j); skewed d to dodge bank conflicts
    int pi = tid >> 4, pj = tid & 15;
    float dot = 0.f;
    for (int dd = 0; dd < kD; ++dd) {
        int d = (dd + tid) & (kD - 1);
        dot += lcn[pi * kD + d] * lcn[pj * kD + d];
    }
    pdm[tid] = 1.f - dot;
    __syncthreads();
    if (tid == 0) {
        unsigned m[kC];
        for (int a = 0; a < kC; ++a) m[a] = 0u;
        float npairs = 0.f;
        for (int a = 0; a < kC; ++a)
            for (int b = a + 1; b < kC; ++b) {
                bool close = (pdm[a * kC + b] <= kBeta) && (lcnt[a] > 0.f) && (lcnt[b] > 0.f);
                if (close) { m[a] |= 1u << b; m[b] |= 1u << a; npairs += 1.f; }
            }
        float count = 0.f;
        for (int a = 0; a < kC; ++a) {
            mask_g[a] = m[a];
            count += (float)__popc(m[a]) * lcnt[a];
        }
        scal[0] = fmaxf(count, 1.f); // denom
        scal[1] = npairs;
    }
}

// ---------------------------------------------------------------- K3: main distance pass
__global__ __launch_bounds__(256) void k3_main(const float* __restrict__ emb,
                                               const int* __restrict__ labels,
                                               const float* __restrict__ cn_g,
                                               const unsigned* __restrict__ mask_g,
                                               float* __restrict__ total,
                                               int N, int half) {
    __shared__ __align__(16) float lcn[kC * kD];  // 32 KB
    __shared__ unsigned lmask[kC];
    __shared__ float wsum[4];
    int tid = threadIdx.x;
    for (int i = tid; i < kC * kD; i += 256) lcn[i] = cn_g[i];
    if (tid < kC) lmask[tid] = mask_g[tid];
    __syncthreads();

    int r0 = blockIdx.x * 256 + tid;
    int r1 = r0 + half;
    bool v0 = (r0 < half) && (r0 < N);
    bool v1 = v0 && (r1 < N);

    float dots0[kC], dots1[kC];
#pragma unroll
    for (int cc = 0; cc < kC; ++cc) { dots0[cc] = 0.f; dots1[cc] = 0.f; }
    float n0 = 0.f, n1 = 0.f;

    // clamp to a valid row so loads stay in-bounds; contribution masked later
    int rr0 = v0 ? r0 : 0;
    int rr1 = v1 ? r1 : 0;
    const float4* row0 = (const float4*)(emb + (size_t)rr0 * kD);
    const float4* row1 = (const float4*)(emb + (size_t)rr1 * kD);
    const float4* w4 = (const float4*)lcn;

    for (int it = 0; it < kD / 4; ++it) {
        float4 x0 = row0[it];
        float4 x1 = row1[it];
        n0 += x0.x * x0.x + x0.y * x0.y + x0.z * x0.z + x0.w * x0.w;
        n1 += x1.x * x1.x + x1.y * x1.y + x1.z * x1.z + x1.w * x1.w;
#pragma unroll
        for (int cc = 0; cc < kC; ++cc) {
            float4 w = w4[cc * (kD / 4) + it];   // wave-uniform -> LDS broadcast
            dots0[cc] += x0.x * w.x + x0.y * w.y + x0.z * w.z + x0.w * w.w;
            dots1[cc] += x1.x * w.x + x1.y * w.y + x1.z * w.z + x1.w * w.w;
        }
    }

    float contrib = 0.f;
    {
        // row 0
        int l = v0 ? labels[rr0] : 0;
        unsigned m = lmask[l];
        float inv = 1.f / fmaxf(sqrtf(n0), kEps);
        float down = 0.f;
#pragma unroll
        for (int cc = 0; cc < kC; ++cc) down = (cc == l) ? (1.f - dots0[cc] * inv) : down;
        float s = (float)__popc(m) * fmaxf(down - kAlpha, 0.f);
#pragma unroll
        for (int cc = 0; cc < kC; ++cc) {
            float dd = 1.f - dots0[cc] * inv;
            s += ((m >> cc) & 1u) ? fmaxf(kBeta - dd, 0.f) : 0.f;
        }
        contrib += v0 ? s : 0.f;
    }
    {
        // row 1
        int l = v1 ? labels[rr1] : 0;
        unsigned m = lmask[l];
        float inv = 1.f / fmaxf(sqrtf(n1), kEps);
        float down = 0.f;
#pragma unroll
        for (int cc = 0; cc < kC; ++cc) down = (cc == l) ? (1.f - dots1[cc] * inv) : down;
        float s = (float)__popc(m) * fmaxf(down - kAlpha, 0.f);
#pragma unroll
        for (int cc = 0; cc < kC; ++cc) {
            float dd = 1.f - dots1[cc] * inv;
            s += ((m >> cc) & 1u) ? fmaxf(kBeta - dd, 0.f) : 0.f;
        }
        contrib += v1 ? s : 0.f;
    }

    // block reduce: wave shuffle then 4 partials
#pragma unroll
    for (int off = 32; off > 0; off >>= 1) contrib += __shfl_down(contrib, off, 64);
    if ((tid & 63) == 0) wsum[tid >> 6] = contrib;
    __syncthreads();
    if (tid == 0) atomicAdd(total, wsum[0] + wsum[1] + wsum[2] + wsum[3]);
}

// ---------------------------------------------------------------- K4: epilogue
__global__ void k4_final(const float* __restrict__ total,
                         const float* __restrict__ scal,
                         float* __restrict__ out) {
    out[0] = (scal[1] > 0.f) ? (total[0] / scal[0]) : 0.f;
}

extern "C" void kernel_launch(void* const* d_in, const int* in_sizes, int n_in,
                              void* d_out, int out_size, void* d_ws, size_t ws_size,
                              hipStream_t stream) {
    const float* emb = (const float*)d_in[0];
    const int* labels = (const int*)d_in[1];
    int N = in_sizes[0] / kD;

    float* ws = (float*)d_ws;
    float* sums = ws + SUMS_OFF;
    float* cnt = ws + CNT_OFF;
    float* total = ws + TOT_OFF;
    float* cn = ws + CN_OFF;
    unsigned* mask = (unsigned*)(ws + MSK_OFF);
    float* scal = ws + SCL_OFF;

    hipMemsetAsync(d_ws, 0, ZERO_FLOATS * sizeof(float), stream);

    int blocks1 = 512;
    int rpb = (N + blocks1 - 1) / blocks1;
    k1_sums<<<blocks1, 256, 0, stream>>>(emb, labels, sums, cnt, N, rpb);

    k2_cent<<<1, 256, 0, stream>>>(sums, cnt, cn, mask, scal);

    int half = (N + 1) >> 1;
    int blocks3 = (half + 255) / 256;
    k3_main<<<blocks3, 256, 0, stream>>>(emb, labels, cn, mask, total, N, half);

    k4_final<<<1, 1, 0, stream>>>(total, scal, (float*)d_out);
}